// Round 8
// baseline (77.333 us; speedup 1.0000x reference)
//
#include <hip/hip_runtime.h>

#define EPS 1e-7f

constexpr int NPRED = 8192;
constexpr int NTGT  = 4096;
constexpr int BLOCK = 256;             // 4 waves
constexpr int PW    = 4;               // preds per wave (LDS read amortized 4x)
constexpr int WAVES = BLOCK / 64;
constexpr int PPB   = WAVES * PW;      // 16 preds per block
constexpr int GRID  = NPRED / PPB;     // 512 blocks -> 2/CU, 8 waves/CU
constexpr int CH    = 1024;            // targets per staged chunk (20 KB LDS)
constexpr int NCH   = NTGT / CH;       // 4 chunks

__global__ __launch_bounds__(BLOCK, 8)
void diou_main(const float4* __restrict__ pred,
               const float4* __restrict__ tgt,
               float* __restrict__ partial) {
  __shared__ float4 sT[CH];            // 16 KB: target boxes
  __shared__ float  sA[CH];            //  4 KB: target areas
  __shared__ float  sP[WAVES];
  const int lane  = threadIdx.x & 63;
  const int wave  = threadIdx.x >> 6;
  const int pbase = blockIdx.x * PPB + wave * PW;

  float4 p[PW];
  float  paeps[PW];
  float  bestV[PW];
  int    bestB[PW];                    // wave-uniform candidate base (c*CH + t0)
#pragma unroll
  for (int i = 0; i < PW; ++i) {
    p[i]     = pred[pbase + i];
    paeps[i] = (p[i].z - p[i].x) * (p[i].w - p[i].y) + EPS;
    bestV[i] = -INFINITY;
    bestB[i] = 0;
  }

  for (int c = 0; c < NCH; ++c) {
    __syncthreads();                   // protect sT/sA reuse across chunks
    for (int t = threadIdx.x; t < CH; t += BLOCK) {
      float4 tb = tgt[c * CH + t];
      sT[t] = tb;
      sA[t] = (tb.z - tb.x) * (tb.w - tb.y);
    }
    __syncthreads();
    const int cb = c * CH;
#pragma unroll 4
    for (int t0 = 0; t0 < CH; t0 += 64) {
      float4 tb = sT[t0 + lane];       // one b128 + one b32 per 4 pairs
      float  ta = sA[t0 + lane];
#pragma unroll
      for (int i = 0; i < PW; ++i) {
        float w = fminf(p[i].z, tb.z) - fmaxf(p[i].x, tb.x);
        float h = fminf(p[i].w, tb.w) - fmaxf(p[i].y, tb.y);
        w = fmaxf(w, 0.f);
        h = fmaxf(h, 0.f);
        float inter = w * h;
        float den   = (paeps[i] + ta) - inter;
        float iou   = inter * __builtin_amdgcn_rcpf(den);
        // strict > keeps FIRST max (lane's candidates ascend in t0);
        // bestB candidate cb+t0 is wave-uniform -> cheap cndmask
        if (iou > bestV[i]) { bestV[i] = iou; bestB[i] = cb + t0; }
      }
    }
  }

  // per-pred cross-lane argmax (tie -> smaller index), then DIoU on lane 0
  float local = 0.f;
#pragma unroll
  for (int i = 0; i < PW; ++i) {
    int   ix = bestB[i] + lane;
    float v  = bestV[i];
    for (int off = 32; off > 0; off >>= 1) {
      float ov = __shfl_down(v, off, 64);
      int   oi = __shfl_down(ix, off, 64);
      if (ov > v || (ov == v && oi < ix)) { v = ov; ix = oi; }
    }
    if (lane == 0) {
      float4 t = tgt[ix];
      // reference reinterprets columns as (cx, cy, w, h)
      float phw = 0.5f * p[i].z, phh = 0.5f * p[i].w;
      float thw = 0.5f * t.z,    thh = 0.5f * t.w;
      float pltx = p[i].x - phw, plty = p[i].y - phh;
      float prbx = p[i].x + phw, prby = p[i].y + phh;
      float tltx = t.x - thw,    tlty = t.y - thh;
      float trbx = t.x + thw,    trby = t.y + thh;

      float iw = fmaxf(fminf(prbx, trbx) - fmaxf(pltx, tltx), 0.f);
      float ih = fmaxf(fminf(prby, trby) - fmaxf(plty, tlty), 0.f);
      float inter = iw * ih;
      float parea = p[i].z * p[i].w;
      float tarea = t.z * t.w;
      float iou   = inter / (parea + tarea - inter + EPS);

      float dx = p[i].x - t.x, dy = p[i].y - t.y;
      float cd = dx * dx + dy * dy;

      float ew = fmaxf(prbx, trbx) - fminf(pltx, tltx);
      float eh = fmaxf(prby, trby) - fminf(plty, tlty);
      float diag = ew * ew + eh * eh;

      local += iou - cd / (diag + EPS);
    }
  }
  if (lane == 0) sP[wave] = local;
  __syncthreads();
  if (threadIdx.x == 0) {
    float s = 0.f;
#pragma unroll
    for (int i = 0; i < WAVES; ++i) s += sP[i];
    partial[blockIdx.x] = s;           // plain store: no init, no atomics
  }
}

__global__ __launch_bounds__(GRID)
void diou_finalize(const float* __restrict__ partial,
                   float* __restrict__ out) {
  __shared__ float sW[GRID / 64];
  const int tid  = threadIdx.x;
  const int lane = tid & 63;
  float v = partial[tid];              // GRID partials, one per thread
  for (int off = 32; off > 0; off >>= 1) v += __shfl_down(v, off, 64);
  if (lane == 0) sW[tid >> 6] = v;
  __syncthreads();
  if (tid == 0) {
    float s = 0.f;
#pragma unroll
    for (int i = 0; i < GRID / 64; ++i) s += sW[i];
    out[0] = 1.f - s * (1.f / (float)NPRED);
  }
}

extern "C" void kernel_launch(void* const* d_in, const int* in_sizes, int n_in,
                              void* d_out, int out_size, void* d_ws, size_t ws_size,
                              hipStream_t stream) {
  const float4* pred = (const float4*)d_in[0];
  const float4* tgt  = (const float4*)d_in[1];
  float* partial = (float*)d_ws;       // GRID * 4 B, fully written each call

  diou_main<<<GRID, BLOCK, 0, stream>>>(pred, tgt, partial);
  diou_finalize<<<1, GRID, 0, stream>>>(partial, (float*)d_out);
}

// Round 13
// 77.120 us; speedup vs baseline: 1.0028x; 1.0028x over previous
//
#include <hip/hip_runtime.h>

#define EPS 1e-7f

constexpr int NPRED = 8192;
constexpr int NTGT  = 4096;
constexpr int BLOCK = 256;             // 4 waves
constexpr int PW    = 2;               // preds per wave (LDS amortize 2x)
constexpr int WAVES = BLOCK / 64;
constexpr int PPB   = WAVES * PW;      // 8 preds per block
constexpr int GRID  = NPRED / PPB;     // 1024 blocks -> 4/CU, 16 waves/CU, 4/SIMD
constexpr int CH    = 1024;            // targets per staged chunk (20 KB LDS)
constexpr int NCH   = NTGT / CH;       // 4 chunks

__global__ __launch_bounds__(BLOCK, 4)   // 4 waves/EU needed; VGPR cap 128
void diou_main(const float4* __restrict__ pred,
               const float4* __restrict__ tgt,
               float* __restrict__ partial) {
  __shared__ float4 sT[CH];            // 16 KB: target boxes
  __shared__ float  sA[CH];            //  4 KB: target areas
  __shared__ float  sP[WAVES];
  const int lane  = threadIdx.x & 63;
  const int wave  = threadIdx.x >> 6;
  const int pbase = blockIdx.x * PPB + wave * PW;

  float4 p[PW];
  float  paeps[PW];
  float  bestV[PW];
  int    bestB[PW];                    // wave-uniform candidate base (c*CH + t0)
#pragma unroll
  for (int i = 0; i < PW; ++i) {
    p[i]     = pred[pbase + i];
    paeps[i] = (p[i].z - p[i].x) * (p[i].w - p[i].y) + EPS;
    bestV[i] = -INFINITY;
    bestB[i] = 0;
  }

  for (int c = 0; c < NCH; ++c) {
    __syncthreads();                   // protect sT/sA reuse across chunks
    for (int t = threadIdx.x; t < CH; t += BLOCK) {
      float4 tb = tgt[c * CH + t];
      sT[t] = tb;
      sA[t] = (tb.z - tb.x) * (tb.w - tb.y);
    }
    __syncthreads();
    const int cb = c * CH;
#pragma unroll 4
    for (int t0 = 0; t0 < CH; t0 += 64) {
      float4 tb = sT[t0 + lane];       // one b128 + one b32 per 2 pairs
      float  ta = sA[t0 + lane];
#pragma unroll
      for (int i = 0; i < PW; ++i) {
        float w = fminf(p[i].z, tb.z) - fmaxf(p[i].x, tb.x);
        float h = fminf(p[i].w, tb.w) - fmaxf(p[i].y, tb.y);
        w = fmaxf(w, 0.f);
        h = fmaxf(h, 0.f);
        float inter = w * h;
        float den   = (paeps[i] + ta) - inter;
        float iou   = inter * __builtin_amdgcn_rcpf(den);
        // strict > keeps FIRST max (lane's candidates ascend in t0);
        // bestB candidate cb+t0 is wave-uniform -> cheap cndmask
        if (iou > bestV[i]) { bestV[i] = iou; bestB[i] = cb + t0; }
      }
    }
  }

  // per-pred cross-lane argmax (tie -> smaller index), then DIoU on lane 0
  float local = 0.f;
#pragma unroll
  for (int i = 0; i < PW; ++i) {
    int   ix = bestB[i] + lane;
    float v  = bestV[i];
    for (int off = 32; off > 0; off >>= 1) {
      float ov = __shfl_down(v, off, 64);
      int   oi = __shfl_down(ix, off, 64);
      if (ov > v || (ov == v && oi < ix)) { v = ov; ix = oi; }
    }
    if (lane == 0) {
      float4 t = tgt[ix];
      // reference reinterprets columns as (cx, cy, w, h)
      float phw = 0.5f * p[i].z, phh = 0.5f * p[i].w;
      float thw = 0.5f * t.z,    thh = 0.5f * t.w;
      float pltx = p[i].x - phw, plty = p[i].y - phh;
      float prbx = p[i].x + phw, prby = p[i].y + phh;
      float tltx = t.x - thw,    tlty = t.y - thh;
      float trbx = t.x + thw,    trby = t.y + thh;

      float iw = fmaxf(fminf(prbx, trbx) - fmaxf(pltx, tltx), 0.f);
      float ih = fmaxf(fminf(prby, trby) - fmaxf(plty, tlty), 0.f);
      float inter = iw * ih;
      float parea = p[i].z * p[i].w;
      float tarea = t.z * t.w;
      float iou   = inter / (parea + tarea - inter + EPS);

      float dx = p[i].x - t.x, dy = p[i].y - t.y;
      float cd = dx * dx + dy * dy;

      float ew = fmaxf(prbx, trbx) - fminf(pltx, tltx);
      float eh = fmaxf(prby, trby) - fminf(plty, tlty);
      float diag = ew * ew + eh * eh;

      local += iou - cd / (diag + EPS);
    }
  }
  if (lane == 0) sP[wave] = local;
  __syncthreads();
  if (threadIdx.x == 0) {
    float s = 0.f;
#pragma unroll
    for (int i = 0; i < WAVES; ++i) s += sP[i];
    partial[blockIdx.x] = s;           // plain store: no init, no atomics
  }
}

__global__ __launch_bounds__(1024)
void diou_finalize(const float* __restrict__ partial,
                   float* __restrict__ out) {
  __shared__ float sW[16];
  const int tid  = threadIdx.x;
  const int lane = tid & 63;
  float v = partial[tid];              // GRID == 1024 partials, one per thread
  for (int off = 32; off > 0; off >>= 1) v += __shfl_down(v, off, 64);
  if (lane == 0) sW[tid >> 6] = v;
  __syncthreads();
  if (tid == 0) {
    float s = 0.f;
#pragma unroll
    for (int i = 0; i < 16; ++i) s += sW[i];
    out[0] = 1.f - s * (1.f / (float)NPRED);
  }
}

extern "C" void kernel_launch(void* const* d_in, const int* in_sizes, int n_in,
                              void* d_out, int out_size, void* d_ws, size_t ws_size,
                              hipStream_t stream) {
  const float4* pred = (const float4*)d_in[0];
  const float4* tgt  = (const float4*)d_in[1];
  float* partial = (float*)d_ws;       // GRID * 4 B, fully written each call

  diou_main<<<GRID, BLOCK, 0, stream>>>(pred, tgt, partial);
  diou_finalize<<<1, 1024, 0, stream>>>(partial, (float*)d_out);
}